// Round 12
// baseline (529.589 us; speedup 1.0000x reference)
//
#include <hip/hip_runtime.h>
#include <hip/hip_bf16.h>
#include <stdint.h>

typedef __attribute__((ext_vector_type(8))) short bf16x8;
typedef __attribute__((ext_vector_type(4))) short s16x4;
typedef __attribute__((ext_vector_type(4))) float f32x4;

__device__ __forceinline__ unsigned short f2b(float x) {
  __hip_bfloat16 h = __float2bfloat16(x);
  unsigned short u;
  __builtin_memcpy(&u, &h, 2);
  return u;
}

__device__ __forceinline__ float b2f(unsigned short u) {
  unsigned v = (unsigned)u << 16;
  float f;
  __builtin_memcpy(&f, &v, 4);
  return f;
}

__device__ __forceinline__ void glds16(const void* g, void* l) {
  __builtin_amdgcn_global_load_lds((const __attribute__((address_space(1))) void*)g,
                                   (__attribute__((address_space(3))) void*)l,
                                   16, 0, 0);
}

// ---------------------------------------------------------------------------
// Fused QKV projection GEMM (m97 structure, 128x128 tile, BK=32, 4 waves).
//   z=0: q  = (h@wq + bq) * qscale   (qscale folds 1/sqrt(C) * log2e)
//   z=1: kk = h@wk + bk
//   z=2: vT = h@wv + bv, stored transposed per batch [B][256][4096], with the
//        position index k-permuted within each 32-chunk:
//        pos(k) = ((k>>2)&3)*8 + ((k>>4)&1)*4 + (k&3)
// ---------------------------------------------------------------------------
__global__ __launch_bounds__(256) void gemm_qkv(
    const unsigned short* __restrict__ h, const unsigned short* __restrict__ wT,
    const float* __restrict__ bq, const float* __restrict__ bk, const float* __restrict__ bv,
    unsigned short* __restrict__ q, unsigned short* __restrict__ kk,
    unsigned short* __restrict__ vT, float qscale)
{
  __shared__ unsigned short As[128 * 32];
  __shared__ unsigned short Bs[128 * 32];
  const int t = threadIdx.x;
  const int lane = t & 63;
  const int wv_ = t >> 6;
  const int wr = wv_ >> 1, wc = wv_ & 1;
  const int z = blockIdx.z;
  const long long row0 = (long long)blockIdx.y * 128;
  const int col0 = blockIdx.x * 128;
  const unsigned short* Bt = wT + z * 65536;
  const float* bias = z == 0 ? bq : z == 1 ? bk : bv;
  const float scale = z == 0 ? qscale : 1.0f;

  const int sr = t >> 2;
  const int sc = (t & 3) * 8;
  const unsigned short* ga = h + (row0 + sr) * 256 + sc;
  const unsigned short* gb = Bt + (col0 + sr) * 256 + sc;
  char* lA = (char*)As + (t >> 6) * 1024;
  char* lB = (char*)Bs + (t >> 6) * 1024;

  const int l15 = lane & 15;
  const int l4 = lane >> 4;
  const unsigned short* pa = As + (wr * 64 + l15) * 32 + l4 * 8;
  const unsigned short* pb = Bs + (wc * 64 + l15) * 32 + l4 * 8;

  f32x4 acc[4][4] = {};

  for (int k0 = 0; k0 < 256; k0 += 32) {
    glds16(ga, lA);
    glds16(ga + 64 * 256, lA + 4096);
    glds16(gb, lB);
    glds16(gb + 64 * 256, lB + 4096);
    ga += 32;
    gb += 32;
    __syncthreads();
    bf16x8 a[4], b[4];
#pragma unroll
    for (int i = 0; i < 4; i++) a[i] = *(const bf16x8*)(pa + i * 512);
#pragma unroll
    for (int j = 0; j < 4; j++) b[j] = *(const bf16x8*)(pb + j * 512);
#pragma unroll
    for (int i = 0; i < 4; i++)
#pragma unroll
      for (int j = 0; j < 4; j++)
        acc[i][j] = __builtin_amdgcn_mfma_f32_16x16x32_bf16(a[i], b[j], acc[i][j], 0, 0, 0);
    __syncthreads();
  }

#pragma unroll
  for (int i = 0; i < 4; i++) {
#pragma unroll
    for (int j = 0; j < 4; j++) {
      const int col = col0 + wc * 64 + j * 16 + l15;
      const float bv_ = bias[col];
#pragma unroll
      for (int r = 0; r < 4; r++) {
        const long long row = row0 + wr * 64 + i * 16 + l4 * 4 + r;
        const float val = (acc[i][j][r] + bv_) * scale;
        if (z == 0) {
          q[row * 256 + col] = f2b(val);
        } else if (z == 1) {
          kk[row * 256 + col] = f2b(val);
        } else {
          const int bb = (int)(row >> 12), rr = (int)(row & 4095);
          const int kl = rr & 31;
          const int rrp = (rr & ~31) | ((((kl >> 2) & 3) << 3) | (((kl >> 4) & 1) << 2) | (kl & 3));
          vT[((long long)bb * 256 + col) * 4096 + rrp] = f2b(val);
        }
      }
    }
  }
}

// ---------------------------------------------------------------------------
// Final projection + residual with FUSED 3-way KV-split merge:
//   A[row] = f0*o0 + f1*o1 + f2*o2, f_i = w_i / sum(w_j*l_j), w_i=exp2(m_i-M)
//   out = x + A@woT + bo   (f32 out)
// ---------------------------------------------------------------------------
__global__ __launch_bounds__(256) void gemm_out(
    const unsigned short* __restrict__ o0, const unsigned short* __restrict__ o1,
    const unsigned short* __restrict__ o2,
    const float2* __restrict__ ml0, const float2* __restrict__ ml1,
    const float2* __restrict__ ml2,
    const unsigned short* __restrict__ Bt,
    float* __restrict__ C, const float* __restrict__ bias,
    const float* __restrict__ resid)
{
  __shared__ unsigned short As[128 * 32];
  __shared__ unsigned short Bs[128 * 32];
  const int t = threadIdx.x;
  const int lane = t & 63;
  const int wv_ = t >> 6;
  const int wr = wv_ >> 1, wc = wv_ & 1;
  const long long row0 = (long long)blockIdx.y * 128;
  const int col0 = blockIdx.x * 128;

  const int sr = t >> 2;
  const int sc = (t & 3) * 8;
  const long long ar0 = row0 + sr;
  float fA[2][3];
#pragma unroll
  for (int rr = 0; rr < 2; rr++) {
    const long long row = ar0 + rr * 64;
    const float2 a = ml0[row], c = ml1[row], d = ml2[row];
    const float M = fmaxf(fmaxf(a.x, c.x), d.x);
    const float w0 = exp2f(a.x - M), w1 = exp2f(c.x - M), w2 = exp2f(d.x - M);
    const float inv = 1.f / (w0 * a.y + w1 * c.y + w2 * d.y);
    fA[rr][0] = w0 * inv;
    fA[rr][1] = w1 * inv;
    fA[rr][2] = w2 * inv;
  }
  const unsigned short* g0 = o0 + ar0 * 256 + sc;
  const unsigned short* g1 = o1 + ar0 * 256 + sc;
  const unsigned short* g2 = o2 + ar0 * 256 + sc;
  const unsigned short* gb = Bt + (col0 + sr) * 256 + sc;
  char* lB = (char*)Bs + (t >> 6) * 1024;

  const int l15 = lane & 15;
  const int l4 = lane >> 4;
  const unsigned short* pa = As + (wr * 64 + l15) * 32 + l4 * 8;
  const unsigned short* pb = Bs + (wc * 64 + l15) * 32 + l4 * 8;

  f32x4 acc[4][4] = {};

  for (int k0 = 0; k0 < 256; k0 += 32) {
#pragma unroll
    for (int rr = 0; rr < 2; rr++) {
      bf16x8 u0 = *(const bf16x8*)(g0 + rr * 64 * 256);
      bf16x8 u1 = *(const bf16x8*)(g1 + rr * 64 * 256);
      bf16x8 u2 = *(const bf16x8*)(g2 + rr * 64 * 256);
      bf16x8 m_;
#pragma unroll
      for (int e = 0; e < 8; e++)
        m_[e] = (short)f2b(fA[rr][0] * b2f((unsigned short)u0[e]) +
                           fA[rr][1] * b2f((unsigned short)u1[e]) +
                           fA[rr][2] * b2f((unsigned short)u2[e]));
      *(bf16x8*)((char*)As + rr * 4096 + t * 16) = m_;
    }
    glds16(gb, lB);
    glds16(gb + 64 * 256, lB + 4096);
    g0 += 32;
    g1 += 32;
    g2 += 32;
    gb += 32;
    __syncthreads();
    bf16x8 a[4], b[4];
#pragma unroll
    for (int i = 0; i < 4; i++) a[i] = *(const bf16x8*)(pa + i * 512);
#pragma unroll
    for (int j = 0; j < 4; j++) b[j] = *(const bf16x8*)(pb + j * 512);
#pragma unroll
    for (int i = 0; i < 4; i++)
#pragma unroll
      for (int j = 0; j < 4; j++)
        acc[i][j] = __builtin_amdgcn_mfma_f32_16x16x32_bf16(a[i], b[j], acc[i][j], 0, 0, 0);
    __syncthreads();
  }

#pragma unroll
  for (int i = 0; i < 4; i++) {
#pragma unroll
    for (int j = 0; j < 4; j++) {
      const int col = col0 + wc * 64 + j * 16 + l15;
      const float bv_ = bias[col];
#pragma unroll
      for (int r = 0; r < 4; r++) {
        const long long row = row0 + wr * 64 + i * 16 + l4 * 4 + r;
        const long long idx = row * 256 + col;
        C[idx] = resid[idx] + acc[i][j][r] + bv_;
      }
    }
  }
}

// ---------------------------------------------------------------------------
// LayerNorm over C=256: one WAVE per row (4 f32 per lane), 8 rows per block.
// ---------------------------------------------------------------------------
__global__ __launch_bounds__(512) void ln_bf16(const float* __restrict__ x,
                                               const float* __restrict__ gamma,
                                               const float* __restrict__ beta,
                                               unsigned short* __restrict__ h)
{
  const int w = threadIdx.x >> 6;
  const int lane = threadIdx.x & 63;
  const long long row = (long long)blockIdx.x * 8 + w;
  const f32x4 v = *(const f32x4*)(x + row * 256 + lane * 4);
  const f32x4 g = *(const f32x4*)(gamma + lane * 4);
  const f32x4 be = *(const f32x4*)(beta + lane * 4);
  float s = v[0] + v[1] + v[2] + v[3];
  float s2 = v[0] * v[0] + v[1] * v[1] + v[2] * v[2] + v[3] * v[3];
#pragma unroll
  for (int o = 32; o >= 1; o >>= 1) {
    s += __shfl_xor(s, o, 64);
    s2 += __shfl_xor(s2, o, 64);
  }
  const float mean = s * (1.f / 256.f);
  const float var = s2 * (1.f / 256.f) - mean * mean;
  const float rstd = rsqrtf(var + 1e-3f);
  s16x4 out;
#pragma unroll
  for (int e = 0; e < 4; e++) out[e] = (short)f2b((v[e] - mean) * rstd * g[e] + be[e]);
  *(s16x4*)(h + row * 256 + lane * 4) = out;
}

// ---------------------------------------------------------------------------
// Transpose + bf16-cast the four 256x256 weights
// ---------------------------------------------------------------------------
__global__ void wtrans(const float* __restrict__ wq, const float* __restrict__ wk,
                       const float* __restrict__ wv, const float* __restrict__ wo,
                       unsigned short* __restrict__ wT)
{
  const float* w = blockIdx.z == 0 ? wq : blockIdx.z == 1 ? wk : blockIdx.z == 2 ? wv : wo;
  unsigned short* o = wT + (long long)blockIdx.z * 65536;
  __shared__ float tile[16][17];
  const int tx = threadIdx.x, ty = threadIdx.y;
  const int bx = blockIdx.x * 16, by = blockIdx.y * 16;
  tile[ty][tx] = w[(by + ty) * 256 + bx + tx];
  __syncthreads();
  o[(bx + ty) * 256 + (by + tx)] = f2b(tile[tx][ty]);
}

// ---------------------------------------------------------------------------
// Fused flash attention, swapped-operand, 3-way KV-SPLIT, 3 blocks/CU.
// grid 768: b = bid&7 (XCD pin), rem = bid>>3, kh = rem%3, qb = rem/3.
// Key ranges: [0,1376) [1376,2752) [2752,4096) -> nit = 43/43/42 KVBLK=32
// tiles (1376 = 43*32, multiple of 32 so vT's 32-chunk k-perm stays aligned).
// LDS 48KB -> 3 blocks/CU (12 waves): K SINGLE-buffered 16KB @0 (restaged
// after the QK-close barrier; latency hides under softmax+PV), V double-
// buffered 2x16KB @16K. Per iter: [vmcnt(0); bar] QK [bar] stage(K,V) SM PV.
// Epilogue slab is bf16 (8KB/wave @ lds+w*8192; f2b before transpose --
// identical rounding since output is bf16 anyway).
// Operand maps identical to R6/R9-R11 (verified): swapped QK, lambda-slot PV
// with k-permuted vT, K rows swizzled ^((key&7)<<4), V rows ^((d&3)<<4),
// pre-swizzled global staging sources. Partials UNNORMALIZED + (m,l);
// gemm_out does the 3-way merge.
// ---------------------------------------------------------------------------
#define FL_LDS (48 * 1024)

__global__ __launch_bounds__(256, 3) void flash(
    const unsigned short* __restrict__ q,   // [B][4096][256] bf16 (scaled by log2e/16)
    const unsigned short* __restrict__ kk,  // [B][4096][256] bf16
    const unsigned short* __restrict__ vT,  // [B][256][4096] bf16, k-permuted per 32
    unsigned short* __restrict__ o0, unsigned short* __restrict__ o1,
    unsigned short* __restrict__ o2,
    float2* __restrict__ ml0, float2* __restrict__ ml1, float2* __restrict__ ml2)
{
  extern __shared__ char lds[];
  const int t = threadIdx.x;
  const int w = t >> 6;
  const int lane = t & 63;
  const int l15 = lane & 15, hi = lane >> 4;
  const int b = blockIdx.x & 7;
  const int rem = blockIdx.x >> 3;
  const int kh = rem % 3;
  const int qb = rem / 3;
  const int nit = (kh == 2) ? 42 : 43;
  const int kbeg = kh * 1376;
  const long long qrow = (long long)b * 4096 + (long long)qb * 128 + w * 32;

  const unsigned short* kbase = kk + (long long)b * 4096 * 256 + (long long)kbeg * 256;
  const unsigned short* vbase = vT + (long long)b * 256 * 4096 + kbeg;

  const int gs_k = (t & 31) ^ ((t >> 5) & 7);
  const unsigned short* Kst = kbase + (t >> 5) * 256 + gs_k * 8;
  const int gs_v = (t & 3) ^ ((t >> 2) & 3);
  const unsigned short* Vst = vbase + (long long)(t >> 2) * 4096 + gs_v * 8;

  // Q fragments (B-operand): Qf[qg][ks]: q-row = qrow + qg*16 + l15, k = ks*32 + hi*8
  bf16x8 Qf[2][8];
#pragma unroll
  for (int qg = 0; qg < 2; qg++) {
    const unsigned short* qp = q + (qrow + qg * 16 + l15) * 256 + hi * 8;
#pragma unroll
    for (int ks = 0; ks < 8; ks++) Qf[qg][ks] = *(const bf16x8*)(qp + ks * 32);
  }

  f32x4 O[2][16] = {};
  float mrow[2] = {-1e30f, -1e30f};
  float lrow[2] = {0.f, 0.f};  // per-lane partial sums (reduced in epilogue)

  auto stageK = [&](int it) {
    const unsigned short* ks_ = Kst + (long long)it * 32 * 256;
    char* kd = lds + w * 1024;
#pragma unroll
    for (int p = 0; p < 4; p++) glds16(ks_ + p * 8 * 256, kd + p * 4096);
  };
  auto stageV = [&](int it, int c) {
    const unsigned short* vs_ = Vst + it * 32;
    char* vd = lds + 16384 + c * 16384 + w * 1024;
#pragma unroll
    for (int p = 0; p < 4; p++) glds16(vs_ + (long long)p * 64 * 4096, vd + p * 4096);
  };

  stageK(0);
  stageV(0, 0);

  for (int it = 0; it < nit; ++it) {
    const int cur = it & 1;
    asm volatile("s_waitcnt vmcnt(0)" ::: "memory");  // K(it), V(it) staged
    __builtin_amdgcn_sched_barrier(0);
    __builtin_amdgcn_s_barrier();  // bar1: V[cur^1] also free (PV(it-1) done)
    const char* Kb = lds;
    const char* Vb = lds + 16384 + cur * 16384;

    // S^T = K Q^T : per (j, qg): 8 k-steps of 16x16x32
    f32x4 S[2][2] = {};
    __builtin_amdgcn_s_setprio(1);
#pragma unroll
    for (int ks = 0; ks < 8; ks++) {
#pragma unroll
      for (int j = 0; j < 2; j++) {
        bf16x8 Kf = *(const bf16x8*)(Kb + (j * 16 + l15) * 512 +
                                     ((ks * 64 + hi * 16) ^ ((l15 & 7) << 4)));
        S[0][j] = __builtin_amdgcn_mfma_f32_16x16x32_bf16(Kf, Qf[0][ks], S[0][j], 0, 0, 0);
        S[1][j] = __builtin_amdgcn_mfma_f32_16x16x32_bf16(Kf, Qf[1][ks], S[1][j], 0, 0, 0);
      }
    }
    __builtin_amdgcn_s_setprio(0);
    __builtin_amdgcn_sched_barrier(0);
    __builtin_amdgcn_s_barrier();  // bar2: all waves done reading K
    if (it < nit - 1) {
      stageK(it + 1);
      stageV(it + 1, cur ^ 1);
    }

    // online softmax: shfl-free common path (R11)
    bf16x8 Pf8[2];
#pragma unroll
    for (int qg = 0; qg < 2; qg++) {
      const float mxl =
          fmaxf(fmaxf(fmaxf(S[qg][0][0], S[qg][0][1]), fmaxf(S[qg][0][2], S[qg][0][3])),
                fmaxf(fmaxf(S[qg][1][0], S[qg][1][1]), fmaxf(S[qg][1][2], S[qg][1][3])));
      if (!__all(mxl <= mrow[qg] + 8.f)) {
        float mx = fmaxf(mxl, __shfl_xor(mxl, 16, 64));
        mx = fmaxf(mx, __shfl_xor(mx, 32, 64));
        const float mn = fmaxf(mrow[qg], mx);
        const float rs_ = exp2f(mrow[qg] - mn);
        mrow[qg] = mn;
        lrow[qg] *= rs_;
#pragma unroll
        for (int dg = 0; dg < 16; dg++) O[qg][dg] *= rs_;
      }
      float sum = 0.f;
      float e[2][4];
#pragma unroll
      for (int j = 0; j < 2; j++)
#pragma unroll
        for (int r = 0; r < 4; r++) {
          e[j][r] = exp2f(S[qg][j][r] - mrow[qg]);
          sum += e[j][r];
        }
      lrow[qg] += sum;
      bf16x8 p;
#pragma unroll
      for (int j = 0; j < 2; j++)
#pragma unroll
        for (int r = 0; r < 4; r++) p[j * 4 + r] = (short)f2b(e[j][r]);
      Pf8[qg] = p;
    }

    // PV: O^T += V' P'  (one 16x16x32 per (qg,dg); V-frag shared across qg)
    __builtin_amdgcn_s_setprio(1);
#pragma unroll
    for (int dg = 0; dg < 16; dg++) {
      bf16x8 Vf8 = *(const bf16x8*)(Vb + (dg * 16 + l15) * 64 +
                                    ((hi * 16) ^ ((l15 & 3) << 4)));
      O[0][dg] = __builtin_amdgcn_mfma_f32_16x16x32_bf16(Vf8, Pf8[0], O[0][dg], 0, 0, 0);
      O[1][dg] = __builtin_amdgcn_mfma_f32_16x16x32_bf16(Vf8, Pf8[1], O[1][dg], 0, 0, 0);
    }
    __builtin_amdgcn_s_setprio(0);
  }

  // epilogue: reduce lrow across hi, bf16 O^T -> 8KB/wave slab -> partial out
  unsigned short* const op = kh == 0 ? o0 : kh == 1 ? o1 : o2;
  float2* const mlp = kh == 0 ? ml0 : kh == 1 ? ml1 : ml2;
  __syncthreads();  // everyone done with K/V buffers
  char* const slab = lds + w * 8192;
#pragma unroll
  for (int qg = 0; qg < 2; qg++) {
    float lr = lrow[qg];
    lr += __shfl_xor(lr, 16, 64);
    lr += __shfl_xor(lr, 32, 64);
#pragma unroll
    for (int dg = 0; dg < 16; dg++) {
      s16x4 pk;
#pragma unroll
      for (int r = 0; r < 4; r++) pk[r] = (short)f2b(O[qg][dg][r]);
      *(s16x4*)(slab + l15 * 512 + ((dg * 32 + hi * 8) ^ ((l15 & 7) << 4))) = pk;
    }
    if (hi == 0) mlp[qrow + qg * 16 + l15] = make_float2(mrow[qg], lr);
    const int qq = lane >> 2;
    const int dc = lane & 3;
    const long long orow = (qrow + qg * 16 + qq) * 256 + dc * 64;
#pragma unroll
    for (int st = 0; st < 8; st++) {
      bf16x8 v = *(const bf16x8*)(slab + qq * 512 +
                                  ((dc * 128 + st * 16) ^ ((qq & 7) << 4)));
      *(bf16x8*)(op + orow + st * 8) = v;
    }
    __syncthreads();  // slab reuse between qg passes
  }
}

// ---------------------------------------------------------------------------
extern "C" void kernel_launch(void* const* d_in, const int* in_sizes, int n_in,
                              void* d_out, int out_size, void* d_ws, size_t ws_size,
                              hipStream_t stream)
{
  const float* x = (const float*)d_in[0];
  const float* gamma = (const float*)d_in[1];
  const float* beta = (const float*)d_in[2];
  const float* wq = (const float*)d_in[3];
  const float* bq = (const float*)d_in[4];
  const float* wk = (const float*)d_in[5];
  const float* bk = (const float*)d_in[6];
  const float* wv = (const float*)d_in[7];
  const float* bv = (const float*)d_in[8];
  const float* wo = (const float*)d_in[9];
  const float* bo = (const float*)d_in[10];

  const int Cc = 256;
  const long long MR = 32768;  // 8 * 4096

  char* base = (char*)d_ws;
  size_t off = 0;
  auto take = [&](size_t bytes) -> char* {
    char* p = base + off;
    off = (off + bytes + 255) & ~(size_t)255;
    return p;
  };
  unsigned short* h   = (unsigned short*)take((size_t)MR * Cc * 2);  // LN out; REUSED as o2
  unsigned short* q   = (unsigned short*)take((size_t)MR * Cc * 2);  // scaled
  unsigned short* kk  = (unsigned short*)take((size_t)MR * Cc * 2);
  unsigned short* vT  = (unsigned short*)take((size_t)MR * Cc * 2);  // [B][C][4096] k-perm
  unsigned short* o0  = (unsigned short*)take((size_t)MR * Cc * 2);  // partial kh=0
  unsigned short* o1  = (unsigned short*)take((size_t)MR * Cc * 2);  // partial kh=1
  unsigned short* o2  = h;  // h is dead after gemm_qkv; alias for partial kh=2
  unsigned short* wT  = (unsigned short*)take(4ull * Cc * Cc * 2);
  float2* ml0 = (float2*)take((size_t)MR * sizeof(float2));
  float2* ml1 = (float2*)take((size_t)MR * sizeof(float2));
  float2* ml2 = (float2*)take((size_t)MR * sizeof(float2));

  wtrans<<<dim3(16, 16, 4), dim3(16, 16), 0, stream>>>(wq, wk, wv, wo, wT);
  ln_bf16<<<dim3((unsigned)(MR / 8)), dim3(512), 0, stream>>>(x, gamma, beta, h);

  const float qscale = 0.0625f * 1.44269504f;  // 1/sqrt(256) * log2(e)
  gemm_qkv<<<dim3(2, 256, 3), 256, 0, stream>>>(h, wT, bq, bk, bv, q, kk, vT, qscale);

  flash<<<dim3(768), dim3(256), FL_LDS, stream>>>(q, kk, vT, o0, o1, o2, ml0, ml1, ml2);

  gemm_out<<<dim3(2, 256, 1), 256, 0, stream>>>(o0, o1, o2, ml0, ml1, ml2,
                                                wT + 3 * 65536, (float*)d_out, bo, x);
}

// Round 13
// 249.440 us; speedup vs baseline: 2.1231x; 2.1231x over previous
//
#include <hip/hip_runtime.h>
#include <hip/hip_bf16.h>
#include <stdint.h>

typedef __attribute__((ext_vector_type(8))) short bf16x8;
typedef __attribute__((ext_vector_type(4))) short s16x4;
typedef __attribute__((ext_vector_type(4))) float f32x4;

__device__ __forceinline__ unsigned short f2b(float x) {
  __hip_bfloat16 h = __float2bfloat16(x);
  unsigned short u;
  __builtin_memcpy(&u, &h, 2);
  return u;
}

__device__ __forceinline__ float b2f(unsigned short u) {
  unsigned v = (unsigned)u << 16;
  float f;
  __builtin_memcpy(&f, &v, 4);
  return f;
}

__device__ __forceinline__ void glds16(const void* g, void* l) {
  __builtin_amdgcn_global_load_lds((const __attribute__((address_space(1))) void*)g,
                                   (__attribute__((address_space(3))) void*)l,
                                   16, 0, 0);
}

// ---------------------------------------------------------------------------
// Fused QKV projection GEMM (m97 structure, 128x128 tile, BK=32, 4 waves).
//   z=0: q  = (h@wq + bq) * qscale   (qscale folds 1/sqrt(C) * log2e)
//   z=1: kk = h@wk + bk
//   z=2: vT = h@wv + bv, stored transposed per batch [B][256][4096], with the
//        position index k-permuted within each 32-chunk:
//        pos(k) = ((k>>2)&3)*8 + ((k>>4)&1)*4 + (k&3)
// ---------------------------------------------------------------------------
__global__ __launch_bounds__(256) void gemm_qkv(
    const unsigned short* __restrict__ h, const unsigned short* __restrict__ wT,
    const float* __restrict__ bq, const float* __restrict__ bk, const float* __restrict__ bv,
    unsigned short* __restrict__ q, unsigned short* __restrict__ kk,
    unsigned short* __restrict__ vT, float qscale)
{
  __shared__ unsigned short As[128 * 32];
  __shared__ unsigned short Bs[128 * 32];
  const int t = threadIdx.x;
  const int lane = t & 63;
  const int wv_ = t >> 6;
  const int wr = wv_ >> 1, wc = wv_ & 1;
  const int z = blockIdx.z;
  const long long row0 = (long long)blockIdx.y * 128;
  const int col0 = blockIdx.x * 128;
  const unsigned short* Bt = wT + z * 65536;
  const float* bias = z == 0 ? bq : z == 1 ? bk : bv;
  const float scale = z == 0 ? qscale : 1.0f;

  const int sr = t >> 2;
  const int sc = (t & 3) * 8;
  const unsigned short* ga = h + (row0 + sr) * 256 + sc;
  const unsigned short* gb = Bt + (col0 + sr) * 256 + sc;
  char* lA = (char*)As + (t >> 6) * 1024;
  char* lB = (char*)Bs + (t >> 6) * 1024;

  const int l15 = lane & 15;
  const int l4 = lane >> 4;
  const unsigned short* pa = As + (wr * 64 + l15) * 32 + l4 * 8;
  const unsigned short* pb = Bs + (wc * 64 + l15) * 32 + l4 * 8;

  f32x4 acc[4][4] = {};

  for (int k0 = 0; k0 < 256; k0 += 32) {
    glds16(ga, lA);
    glds16(ga + 64 * 256, lA + 4096);
    glds16(gb, lB);
    glds16(gb + 64 * 256, lB + 4096);
    ga += 32;
    gb += 32;
    __syncthreads();
    bf16x8 a[4], b[4];
#pragma unroll
    for (int i = 0; i < 4; i++) a[i] = *(const bf16x8*)(pa + i * 512);
#pragma unroll
    for (int j = 0; j < 4; j++) b[j] = *(const bf16x8*)(pb + j * 512);
#pragma unroll
    for (int i = 0; i < 4; i++)
#pragma unroll
      for (int j = 0; j < 4; j++)
        acc[i][j] = __builtin_amdgcn_mfma_f32_16x16x32_bf16(a[i], b[j], acc[i][j], 0, 0, 0);
    __syncthreads();
  }

#pragma unroll
  for (int i = 0; i < 4; i++) {
#pragma unroll
    for (int j = 0; j < 4; j++) {
      const int col = col0 + wc * 64 + j * 16 + l15;
      const float bv_ = bias[col];
#pragma unroll
      for (int r = 0; r < 4; r++) {
        const long long row = row0 + wr * 64 + i * 16 + l4 * 4 + r;
        const float val = (acc[i][j][r] + bv_) * scale;
        if (z == 0) {
          q[row * 256 + col] = f2b(val);
        } else if (z == 1) {
          kk[row * 256 + col] = f2b(val);
        } else {
          const int bb = (int)(row >> 12), rr = (int)(row & 4095);
          const int kl = rr & 31;
          const int rrp = (rr & ~31) | ((((kl >> 2) & 3) << 3) | (((kl >> 4) & 1) << 2) | (kl & 3));
          vT[((long long)bb * 256 + col) * 4096 + rrp] = f2b(val);
        }
      }
    }
  }
}

// ---------------------------------------------------------------------------
// Final projection + residual with FUSED 3-way KV-split merge:
//   A[row] = f0*o0 + f1*o1 + f2*o2, f_i = w_i / sum(w_j*l_j), w_i=exp2(m_i-M)
//   out = x + A@woT + bo   (f32 out)
// ---------------------------------------------------------------------------
__global__ __launch_bounds__(256) void gemm_out(
    const unsigned short* __restrict__ o0, const unsigned short* __restrict__ o1,
    const unsigned short* __restrict__ o2,
    const float2* __restrict__ ml0, const float2* __restrict__ ml1,
    const float2* __restrict__ ml2,
    const unsigned short* __restrict__ Bt,
    float* __restrict__ C, const float* __restrict__ bias,
    const float* __restrict__ resid)
{
  __shared__ unsigned short As[128 * 32];
  __shared__ unsigned short Bs[128 * 32];
  const int t = threadIdx.x;
  const int lane = t & 63;
  const int wv_ = t >> 6;
  const int wr = wv_ >> 1, wc = wv_ & 1;
  const long long row0 = (long long)blockIdx.y * 128;
  const int col0 = blockIdx.x * 128;

  const int sr = t >> 2;
  const int sc = (t & 3) * 8;
  const long long ar0 = row0 + sr;
  float fA[2][3];
#pragma unroll
  for (int rr = 0; rr < 2; rr++) {
    const long long row = ar0 + rr * 64;
    const float2 a = ml0[row], c = ml1[row], d = ml2[row];
    const float M = fmaxf(fmaxf(a.x, c.x), d.x);
    const float w0 = exp2f(a.x - M), w1 = exp2f(c.x - M), w2 = exp2f(d.x - M);
    const float inv = 1.f / (w0 * a.y + w1 * c.y + w2 * d.y);
    fA[rr][0] = w0 * inv;
    fA[rr][1] = w1 * inv;
    fA[rr][2] = w2 * inv;
  }
  const unsigned short* g0 = o0 + ar0 * 256 + sc;
  const unsigned short* g1 = o1 + ar0 * 256 + sc;
  const unsigned short* g2 = o2 + ar0 * 256 + sc;
  const unsigned short* gb = Bt + (col0 + sr) * 256 + sc;
  char* lB = (char*)Bs + (t >> 6) * 1024;

  const int l15 = lane & 15;
  const int l4 = lane >> 4;
  const unsigned short* pa = As + (wr * 64 + l15) * 32 + l4 * 8;
  const unsigned short* pb = Bs + (wc * 64 + l15) * 32 + l4 * 8;

  f32x4 acc[4][4] = {};

  for (int k0 = 0; k0 < 256; k0 += 32) {
#pragma unroll
    for (int rr = 0; rr < 2; rr++) {
      bf16x8 u0 = *(const bf16x8*)(g0 + rr * 64 * 256);
      bf16x8 u1 = *(const bf16x8*)(g1 + rr * 64 * 256);
      bf16x8 u2 = *(const bf16x8*)(g2 + rr * 64 * 256);
      bf16x8 m_;
#pragma unroll
      for (int e = 0; e < 8; e++)
        m_[e] = (short)f2b(fA[rr][0] * b2f((unsigned short)u0[e]) +
                           fA[rr][1] * b2f((unsigned short)u1[e]) +
                           fA[rr][2] * b2f((unsigned short)u2[e]));
      *(bf16x8*)((char*)As + rr * 4096 + t * 16) = m_;
    }
    glds16(gb, lB);
    glds16(gb + 64 * 256, lB + 4096);
    g0 += 32;
    g1 += 32;
    g2 += 32;
    gb += 32;
    __syncthreads();
    bf16x8 a[4], b[4];
#pragma unroll
    for (int i = 0; i < 4; i++) a[i] = *(const bf16x8*)(pa + i * 512);
#pragma unroll
    for (int j = 0; j < 4; j++) b[j] = *(const bf16x8*)(pb + j * 512);
#pragma unroll
    for (int i = 0; i < 4; i++)
#pragma unroll
      for (int j = 0; j < 4; j++)
        acc[i][j] = __builtin_amdgcn_mfma_f32_16x16x32_bf16(a[i], b[j], acc[i][j], 0, 0, 0);
    __syncthreads();
  }

#pragma unroll
  for (int i = 0; i < 4; i++) {
#pragma unroll
    for (int j = 0; j < 4; j++) {
      const int col = col0 + wc * 64 + j * 16 + l15;
      const float bv_ = bias[col];
#pragma unroll
      for (int r = 0; r < 4; r++) {
        const long long row = row0 + wr * 64 + i * 16 + l4 * 4 + r;
        const long long idx = row * 256 + col;
        C[idx] = resid[idx] + acc[i][j][r] + bv_;
      }
    }
  }
}

// ---------------------------------------------------------------------------
// LayerNorm over C=256: one WAVE per row (4 f32 per lane), 8 rows per block.
// ---------------------------------------------------------------------------
__global__ __launch_bounds__(512) void ln_bf16(const float* __restrict__ x,
                                               const float* __restrict__ gamma,
                                               const float* __restrict__ beta,
                                               unsigned short* __restrict__ h)
{
  const int w = threadIdx.x >> 6;
  const int lane = threadIdx.x & 63;
  const long long row = (long long)blockIdx.x * 8 + w;
  const f32x4 v = *(const f32x4*)(x + row * 256 + lane * 4);
  const f32x4 g = *(const f32x4*)(gamma + lane * 4);
  const f32x4 be = *(const f32x4*)(beta + lane * 4);
  float s = v[0] + v[1] + v[2] + v[3];
  float s2 = v[0] * v[0] + v[1] * v[1] + v[2] * v[2] + v[3] * v[3];
#pragma unroll
  for (int o = 32; o >= 1; o >>= 1) {
    s += __shfl_xor(s, o, 64);
    s2 += __shfl_xor(s2, o, 64);
  }
  const float mean = s * (1.f / 256.f);
  const float var = s2 * (1.f / 256.f) - mean * mean;
  const float rstd = rsqrtf(var + 1e-3f);
  s16x4 out;
#pragma unroll
  for (int e = 0; e < 4; e++) out[e] = (short)f2b((v[e] - mean) * rstd * g[e] + be[e]);
  *(s16x4*)(h + row * 256 + lane * 4) = out;
}

// ---------------------------------------------------------------------------
// Transpose + bf16-cast the four 256x256 weights
// ---------------------------------------------------------------------------
__global__ void wtrans(const float* __restrict__ wq, const float* __restrict__ wk,
                       const float* __restrict__ wv, const float* __restrict__ wo,
                       unsigned short* __restrict__ wT)
{
  const float* w = blockIdx.z == 0 ? wq : blockIdx.z == 1 ? wk : blockIdx.z == 2 ? wv : wo;
  unsigned short* o = wT + (long long)blockIdx.z * 65536;
  __shared__ float tile[16][17];
  const int tx = threadIdx.x, ty = threadIdx.y;
  const int bx = blockIdx.x * 16, by = blockIdx.y * 16;
  tile[ty][tx] = w[(by + ty) * 256 + bx + tx];
  __syncthreads();
  o[(bx + ty) * 256 + (by + tx)] = f2b(tile[tx][ty]);
}

// ---------------------------------------------------------------------------
// Fused flash attention, swapped-operand, 3-way KV-SPLIT, 3 blocks/CU.
// grid 768: b = bid&7 (XCD pin), rem = bid>>3, kh = rem%3, qb = rem/3.
// Key ranges [0,1376) [1376,2752) [2752,4096): nit = 43/43/42 KVBLK=32 tiles
// (1376 = 43*32: vT's 32-chunk k-perm stays aligned).
// LDS 48KB -> 3 blocks/CU: K DOUBLE-buffered 2x16KB @0, V SINGLE 16KB @32K.
// VGPR budget: __launch_bounds__(256,2) (NOT ,3 -- that forced an 84-reg cap
// and spilled O to scratch in R12: 1.35GB scratch FETCH). Compiler uses ~128
// VGPR naturally -> 3 waves/SIMD fits (<=170).
// Per-iter schedule:
//   barA [compute(it-1) done: vbuf + kb[cur^1] free]
//   stageV(it) -> vbuf ; stageK(it+1) -> kb[cur^1]
//   vmcnt(8) [drains K(it), staged last iter] ; barB
//   QK(it) on kb[cur] ; softmax (shfl-free, defer-rescale)
//   vmcnt(4) [drains V(it); K(it+1) stays in flight] ; barC
//   PV(it) on vbuf
// Operand maps identical to R6/R9-R11 (verified). Partials UNNORMALIZED +
// (m,l); gemm_out does the 3-way merge. bf16 slab epilogue (R12-verified).
// ---------------------------------------------------------------------------
#define FL_LDS (48 * 1024)

__global__ __launch_bounds__(256, 2) void flash(
    const unsigned short* __restrict__ q,   // [B][4096][256] bf16 (scaled by log2e/16)
    const unsigned short* __restrict__ kk,  // [B][4096][256] bf16
    const unsigned short* __restrict__ vT,  // [B][256][4096] bf16, k-permuted per 32
    unsigned short* __restrict__ o0, unsigned short* __restrict__ o1,
    unsigned short* __restrict__ o2,
    float2* __restrict__ ml0, float2* __restrict__ ml1, float2* __restrict__ ml2)
{
  extern __shared__ char lds[];
  const int t = threadIdx.x;
  const int w = t >> 6;
  const int lane = t & 63;
  const int l15 = lane & 15, hi = lane >> 4;
  const int b = blockIdx.x & 7;
  const int rem = blockIdx.x >> 3;
  const int kh = rem % 3;
  const int qb = rem / 3;
  const int nit = (kh == 2) ? 42 : 43;
  const int kbeg = kh * 1376;
  const long long qrow = (long long)b * 4096 + (long long)qb * 128 + w * 32;

  const unsigned short* kbase = kk + (long long)b * 4096 * 256 + (long long)kbeg * 256;
  const unsigned short* vbase = vT + (long long)b * 256 * 4096 + kbeg;

  const int gs_k = (t & 31) ^ ((t >> 5) & 7);
  const unsigned short* Kst = kbase + (t >> 5) * 256 + gs_k * 8;
  const int gs_v = (t & 3) ^ ((t >> 2) & 3);
  const unsigned short* Vst = vbase + (long long)(t >> 2) * 4096 + gs_v * 8;

  // Q fragments (B-operand): Qf[qg][ks]: q-row = qrow + qg*16 + l15, k = ks*32 + hi*8
  bf16x8 Qf[2][8];
#pragma unroll
  for (int qg = 0; qg < 2; qg++) {
    const unsigned short* qp = q + (qrow + qg * 16 + l15) * 256 + hi * 8;
#pragma unroll
    for (int ks = 0; ks < 8; ks++) Qf[qg][ks] = *(const bf16x8*)(qp + ks * 32);
  }

  f32x4 O[2][16] = {};
  float mrow[2] = {-1e30f, -1e30f};
  float lrow[2] = {0.f, 0.f};  // per-lane partial sums (reduced in epilogue)

  auto stageK = [&](int it, int c) {
    const unsigned short* ks_ = Kst + (long long)it * 32 * 256;
    char* kd = lds + c * 16384 + w * 1024;
#pragma unroll
    for (int p = 0; p < 4; p++) glds16(ks_ + p * 8 * 256, kd + p * 4096);
  };
  auto stageV = [&](int it) {
    const unsigned short* vs_ = Vst + it * 32;
    char* vd = lds + 32768 + w * 1024;
#pragma unroll
    for (int p = 0; p < 4; p++) glds16(vs_ + (long long)p * 64 * 4096, vd + p * 4096);
  };

  stageK(0, 0);

  for (int it = 0; it < nit; ++it) {
    const int cur = it & 1;
    __builtin_amdgcn_s_barrier();  // A: compute(it-1) done -> vbuf, kb[cur^1] free
    stageV(it);
    const int nxt = (it + 1 < nit) ? it + 1 : it;  // clamp (redundant restage on last)
    stageK(nxt, cur ^ 1);
    asm volatile("s_waitcnt vmcnt(8)" ::: "memory");  // K(it) landed (my wave)
    __builtin_amdgcn_sched_barrier(0);
    __builtin_amdgcn_s_barrier();  // B: K(it) landed for all waves
    const char* Kb = lds + cur * 16384;
    const char* Vb = lds + 32768;

    // S^T = K Q^T : per (j, qg): 8 k-steps of 16x16x32
    f32x4 S[2][2] = {};
    __builtin_amdgcn_s_setprio(1);
#pragma unroll
    for (int ks = 0; ks < 8; ks++) {
#pragma unroll
      for (int j = 0; j < 2; j++) {
        bf16x8 Kf = *(const bf16x8*)(Kb + (j * 16 + l15) * 512 +
                                     ((ks * 64 + hi * 16) ^ ((l15 & 7) << 4)));
        S[0][j] = __builtin_amdgcn_mfma_f32_16x16x32_bf16(Kf, Qf[0][ks], S[0][j], 0, 0, 0);
        S[1][j] = __builtin_amdgcn_mfma_f32_16x16x32_bf16(Kf, Qf[1][ks], S[1][j], 0, 0, 0);
      }
    }
    __builtin_amdgcn_s_setprio(0);

    // online softmax: shfl-free common path (R11)
    bf16x8 Pf8[2];
#pragma unroll
    for (int qg = 0; qg < 2; qg++) {
      const float mxl =
          fmaxf(fmaxf(fmaxf(S[qg][0][0], S[qg][0][1]), fmaxf(S[qg][0][2], S[qg][0][3])),
                fmaxf(fmaxf(S[qg][1][0], S[qg][1][1]), fmaxf(S[qg][1][2], S[qg][1][3])));
      if (!__all(mxl <= mrow[qg] + 8.f)) {
        float mx = fmaxf(mxl, __shfl_xor(mxl, 16, 64));
        mx = fmaxf(mx, __shfl_xor(mx, 32, 64));
        const float mn = fmaxf(mrow[qg], mx);
        const float rs_ = exp2f(mrow[qg] - mn);
        mrow[qg] = mn;
        lrow[qg] *= rs_;
#pragma unroll
        for (int dg = 0; dg < 16; dg++) O[qg][dg] *= rs_;
      }
      float sum = 0.f;
      float e[2][4];
#pragma unroll
      for (int j = 0; j < 2; j++)
#pragma unroll
        for (int r = 0; r < 4; r++) {
          e[j][r] = exp2f(S[qg][j][r] - mrow[qg]);
          sum += e[j][r];
        }
      lrow[qg] += sum;
      bf16x8 p;
#pragma unroll
      for (int j = 0; j < 2; j++)
#pragma unroll
        for (int r = 0; r < 4; r++) p[j * 4 + r] = (short)f2b(e[j][r]);
      Pf8[qg] = p;
    }

    asm volatile("s_waitcnt vmcnt(4)" ::: "memory");  // V(it) landed (K(it+1) in flight)
    __builtin_amdgcn_sched_barrier(0);
    __builtin_amdgcn_s_barrier();  // C: V(it) landed for all waves

    // PV: O^T += V' P'  (one 16x16x32 per (qg,dg); V-frag shared across qg)
    __builtin_amdgcn_s_setprio(1);
#pragma unroll
    for (int dg = 0; dg < 16; dg++) {
      bf16x8 Vf8 = *(const bf16x8*)(Vb + (dg * 16 + l15) * 64 +
                                    ((hi * 16) ^ ((l15 & 3) << 4)));
      O[0][dg] = __builtin_amdgcn_mfma_f32_16x16x32_bf16(Vf8, Pf8[0], O[0][dg], 0, 0, 0);
      O[1][dg] = __builtin_amdgcn_mfma_f32_16x16x32_bf16(Vf8, Pf8[1], O[1][dg], 0, 0, 0);
    }
    __builtin_amdgcn_s_setprio(0);
  }

  // epilogue: reduce lrow across hi, bf16 O^T -> 8KB/wave slab -> partial out
  unsigned short* const op = kh == 0 ? o0 : kh == 1 ? o1 : o2;
  float2* const mlp = kh == 0 ? ml0 : kh == 1 ? ml1 : ml2;
  __syncthreads();  // drains vmcnt + all waves done with K/V buffers
  char* const slab = lds + w * 8192;
#pragma unroll
  for (int qg = 0; qg < 2; qg++) {
    float lr = lrow[qg];
    lr += __shfl_xor(lr, 16, 64);
    lr += __shfl_xor(lr, 32, 64);
#pragma unroll
    for (int dg = 0; dg < 16; dg++) {
      s16x4 pk;
#pragma unroll
      for (int r = 0; r < 4; r++) pk[r] = (short)f2b(O[qg][dg][r]);
      *(s16x4*)(slab + l15 * 512 + ((dg * 32 + hi * 8) ^ ((l15 & 7) << 4))) = pk;
    }
    if (hi == 0) mlp[qrow + qg * 16 + l15] = make_float2(mrow[qg], lr);
    const int qq = lane >> 2;
    const int dc = lane & 3;
    const long long orow = (qrow + qg * 16 + qq) * 256 + dc * 64;
#pragma unroll
    for (int st = 0; st < 8; st++) {
      bf16x8 v = *(const bf16x8*)(slab + qq * 512 +
                                  ((dc * 128 + st * 16) ^ ((qq & 7) << 4)));
      *(bf16x8*)(op + orow + st * 8) = v;
    }
    __syncthreads();  // slab reuse between qg passes
  }
}

// ---------------------------------------------------------------------------
extern "C" void kernel_launch(void* const* d_in, const int* in_sizes, int n_in,
                              void* d_out, int out_size, void* d_ws, size_t ws_size,
                              hipStream_t stream)
{
  const float* x = (const float*)d_in[0];
  const float* gamma = (const float*)d_in[1];
  const float* beta = (const float*)d_in[2];
  const float* wq = (const float*)d_in[3];
  const float* bq = (const float*)d_in[4];
  const float* wk = (const float*)d_in[5];
  const float* bk = (const float*)d_in[6];
  const float* wv = (const float*)d_in[7];
  const float* bv = (const float*)d_in[8];
  const float* wo = (const float*)d_in[9];
  const float* bo = (const float*)d_in[10];

  const int Cc = 256;
  const long long MR = 32768;  // 8 * 4096

  char* base = (char*)d_ws;
  size_t off = 0;
  auto take = [&](size_t bytes) -> char* {
    char* p = base + off;
    off = (off + bytes + 255) & ~(size_t)255;
    return p;
  };
  unsigned short* h   = (unsigned short*)take((size_t)MR * Cc * 2);  // LN out; REUSED as o2
  unsigned short* q   = (unsigned short*)take((size_t)MR * Cc * 2);  // scaled
  unsigned short* kk  = (unsigned short*)take((size_t)MR * Cc * 2);
  unsigned short* vT  = (unsigned short*)take((size_t)MR * Cc * 2);  // [B][C][4096] k-perm
  unsigned short* o0  = (unsigned short*)take((size_t)MR * Cc * 2);  // partial kh=0
  unsigned short* o1  = (unsigned short*)take((size_t)MR * Cc * 2);  // partial kh=1
  unsigned short* o2  = h;  // h is dead after gemm_qkv; alias for partial kh=2
  unsigned short* wT  = (unsigned short*)take(4ull * Cc * Cc * 2);
  float2* ml0 = (float2*)take((size_t)MR * sizeof(float2));
  float2* ml1 = (float2*)take((size_t)MR * sizeof(float2));
  float2* ml2 = (float2*)take((size_t)MR * sizeof(float2));

  wtrans<<<dim3(16, 16, 4), dim3(16, 16), 0, stream>>>(wq, wk, wv, wo, wT);
  ln_bf16<<<dim3((unsigned)(MR / 8)), dim3(512), 0, stream>>>(x, gamma, beta, h);

  const float qscale = 0.0625f * 1.44269504f;  // 1/sqrt(256) * log2(e)
  gemm_qkv<<<dim3(2, 256, 3), 256, 0, stream>>>(h, wT, bq, bk, bv, q, kk, vT, qscale);

  flash<<<dim3(768), dim3(256), FL_LDS, stream>>>(q, kk, vT, o0, o1, o2, ml0, ml1, ml2);

  gemm_out<<<dim3(2, 256, 1), 256, 0, stream>>>(o0, o1, o2, ml0, ml1, ml2,
                                                wT + 3 * 65536, (float*)d_out, bo, x);
}

// Round 14
// 219.143 us; speedup vs baseline: 2.4166x; 1.1383x over previous
//
#include <hip/hip_runtime.h>
#include <hip/hip_bf16.h>
#include <stdint.h>

typedef __attribute__((ext_vector_type(8))) short bf16x8;
typedef __attribute__((ext_vector_type(4))) short s16x4;
typedef __attribute__((ext_vector_type(4))) float f32x4;

__device__ __forceinline__ unsigned short f2b(float x) {
  __hip_bfloat16 h = __float2bfloat16(x);
  unsigned short u;
  __builtin_memcpy(&u, &h, 2);
  return u;
}

__device__ __forceinline__ float b2f(unsigned short u) {
  unsigned v = (unsigned)u << 16;
  float f;
  __builtin_memcpy(&f, &v, 4);
  return f;
}

__device__ __forceinline__ void glds16(const void* g, void* l) {
  __builtin_amdgcn_global_load_lds((const __attribute__((address_space(1))) void*)g,
                                   (__attribute__((address_space(3))) void*)l,
                                   16, 0, 0);
}

// ---------------------------------------------------------------------------
// FUSED LayerNorm + QKV projection.
// grid (2, 256): block covers rows row0=by*128, output cols col0=bx*128.
// Phase 1 (LN): each wave LN-normalizes 32 rows of x (f32) via full-wave
//   shfl reduce and stores bf16 into a RESIDENT swizzled LDS A-tile
//   [128][256] (64KB, byte = row*512 + k*2, ^((row&7)<<4)). h never
//   touches global memory; x is read once.
// Phase 2: for z in {q,k,v}: 8 K-steps of 32 with B double-buffered (8KB
//   tiles via glds16), A-frags read from the resident tile (same swizzle
//   algebra as flash's K-reads -> bank-optimal). acc reset per z.
// Epilogues identical to the verified gemm_qkv:
//   z=0: q  = (.+bq)*qscale   z=1: kk = .+bk
//   z=2: vT transposed per batch [B][256][4096] with per-32 k-perm
//        pos(k) = ((k>>2)&3)*8 + ((k>>4)&1)*4 + (k&3)
// LDS 80KB -> 2 blocks/CU.
// ---------------------------------------------------------------------------
#define LQ_LDS (80 * 1024)

__global__ __launch_bounds__(256, 2) void ln_qkv(
    const float* __restrict__ x, const float* __restrict__ gamma,
    const float* __restrict__ beta, const unsigned short* __restrict__ wT,
    const float* __restrict__ bq, const float* __restrict__ bk,
    const float* __restrict__ bv,
    unsigned short* __restrict__ q, unsigned short* __restrict__ kk,
    unsigned short* __restrict__ vT, float qscale)
{
  extern __shared__ char lds[];  // As 64KB @0, Bs 2x8KB @65536
  const int t = threadIdx.x;
  const int lane = t & 63;
  const int w = t >> 6;
  const int wr = w >> 1, wc = w & 1;
  const long long row0 = (long long)blockIdx.y * 128;
  const int col0 = blockIdx.x * 128;

  const int sr = t >> 2;        // B staging row (col idx within 64)
  const int sc = (t & 3) * 8;   // B staging k-offset

  auto stageB = [&](int st, int c) {
    const unsigned short* gb = wT + (st >> 3) * 65536 +
                               (long long)(col0 + sr) * 256 + (st & 7) * 32 + sc;
    char* d = lds + 65536 + c * 8192 + w * 1024;
    glds16(gb, d);
    glds16(gb + 64 * 256, d + 4096);
  };

  stageB(0, 0);  // overlap with LN phase

  // ---- Phase 1: LN into resident swizzled A-tile ----
  {
    const f32x4 g4 = *(const f32x4*)(gamma + lane * 4);
    const f32x4 b4 = *(const f32x4*)(beta + lane * 4);
    for (int rr = 0; rr < 32; rr++) {
      const int rl = w * 32 + rr;
      const f32x4 v = *(const f32x4*)(x + (row0 + rl) * 256 + lane * 4);
      float s = v[0] + v[1] + v[2] + v[3];
      float s2 = v[0] * v[0] + v[1] * v[1] + v[2] * v[2] + v[3] * v[3];
#pragma unroll
      for (int o = 32; o >= 1; o >>= 1) {
        s += __shfl_xor(s, o, 64);
        s2 += __shfl_xor(s2, o, 64);
      }
      const float mean = s * (1.f / 256.f);
      const float var = s2 * (1.f / 256.f) - mean * mean;
      const float rstd = rsqrtf(var + 1e-3f);
      s16x4 hv;
#pragma unroll
      for (int e = 0; e < 4; e++) hv[e] = (short)f2b((v[e] - mean) * rstd * g4[e] + b4[e]);
      *(s16x4*)(lds + ((rl * 512 + lane * 8) ^ ((rl & 7) << 4))) = hv;
    }
  }

  // ---- Phase 2: three GEMMs against the resident A-tile ----
  const int l15 = lane & 15;
  const int l4 = lane >> 4;
  int step = 0;
#pragma unroll
  for (int z = 0; z < 3; z++) {
    f32x4 acc[4][4] = {};
#pragma unroll
    for (int k0 = 0; k0 < 8; k0++, step++) {
      const int cur = step & 1;
      __syncthreads();  // As ready (step0) / Bs[cur] staged; drains vmcnt
      if (step < 23) stageB(step + 1, cur ^ 1);
      bf16x8 a[4], b[4];
#pragma unroll
      for (int i = 0; i < 4; i++) {
        const int row = wr * 64 + i * 16 + l15;
        a[i] = *(const bf16x8*)(lds + ((row * 512 + k0 * 64 + l4 * 16) ^ ((l15 & 7) << 4)));
      }
      const char* pb = lds + 65536 + cur * 8192;
#pragma unroll
      for (int j = 0; j < 4; j++)
        b[j] = *(const bf16x8*)(pb + (wc * 64 + j * 16 + l15) * 64 + l4 * 16);
#pragma unroll
      for (int i = 0; i < 4; i++)
#pragma unroll
        for (int j = 0; j < 4; j++)
          acc[i][j] = __builtin_amdgcn_mfma_f32_16x16x32_bf16(a[i], b[j], acc[i][j], 0, 0, 0);
    }
    // epilogue for z (register-only; no LDS hazard with next z's staging)
    const float* bias = z == 0 ? bq : z == 1 ? bk : bv;
    const float scale = z == 0 ? qscale : 1.0f;
#pragma unroll
    for (int i = 0; i < 4; i++) {
#pragma unroll
      for (int j = 0; j < 4; j++) {
        const int col = col0 + wc * 64 + j * 16 + l15;
        const float bv_ = bias[col];
#pragma unroll
        for (int r = 0; r < 4; r++) {
          const long long row = row0 + wr * 64 + i * 16 + l4 * 4 + r;
          const float val = (acc[i][j][r] + bv_) * scale;
          if (z == 0) {
            q[row * 256 + col] = f2b(val);
          } else if (z == 1) {
            kk[row * 256 + col] = f2b(val);
          } else {
            const int bb = (int)(row >> 12), rr = (int)(row & 4095);
            const int kl = rr & 31;
            const int rrp = (rr & ~31) |
                            ((((kl >> 2) & 3) << 3) | (((kl >> 4) & 1) << 2) | (kl & 3));
            vT[((long long)bb * 256 + col) * 4096 + rrp] = f2b(val);
          }
        }
      }
    }
  }
}

// ---------------------------------------------------------------------------
// Final projection + residual with FUSED KV-half merge (R11-verified):
//   A[row] = f0*o0[row] + f1*o1[row], f_i = w_i / (w0*l0 + w1*l1)
//   out = x + A@woT + bo   (f32 out)
// ---------------------------------------------------------------------------
__global__ __launch_bounds__(256) void gemm_out(
    const unsigned short* __restrict__ o0, const unsigned short* __restrict__ o1,
    const float2* __restrict__ ml0, const float2* __restrict__ ml1,
    const unsigned short* __restrict__ Bt,
    float* __restrict__ C, const float* __restrict__ bias,
    const float* __restrict__ resid)
{
  __shared__ unsigned short As[128 * 32];
  __shared__ unsigned short Bs[128 * 32];
  const int t = threadIdx.x;
  const int lane = t & 63;
  const int wv_ = t >> 6;
  const int wr = wv_ >> 1, wc = wv_ & 1;
  const long long row0 = (long long)blockIdx.y * 128;
  const int col0 = blockIdx.x * 128;

  const int sr = t >> 2;
  const int sc = (t & 3) * 8;
  const long long ar0 = row0 + sr;
  float f0a, f1a, f0b, f1b;
  {
    const float2 a = ml0[ar0], c = ml1[ar0];
    const float M = fmaxf(a.x, c.x);
    const float w0 = exp2f(a.x - M), w1 = exp2f(c.x - M);
    const float inv = 1.f / (w0 * a.y + w1 * c.y);
    f0a = w0 * inv;
    f1a = w1 * inv;
  }
  {
    const float2 a = ml0[ar0 + 64], c = ml1[ar0 + 64];
    const float M = fmaxf(a.x, c.x);
    const float w0 = exp2f(a.x - M), w1 = exp2f(c.x - M);
    const float inv = 1.f / (w0 * a.y + w1 * c.y);
    f0b = w0 * inv;
    f1b = w1 * inv;
  }
  const unsigned short* g0 = o0 + ar0 * 256 + sc;
  const unsigned short* g1 = o1 + ar0 * 256 + sc;
  const unsigned short* gb = Bt + (col0 + sr) * 256 + sc;
  char* lB = (char*)Bs + (t >> 6) * 1024;

  const int l15 = lane & 15;
  const int l4 = lane >> 4;
  const unsigned short* pa = As + (wr * 64 + l15) * 32 + l4 * 8;
  const unsigned short* pb = Bs + (wc * 64 + l15) * 32 + l4 * 8;

  f32x4 acc[4][4] = {};

  for (int k0 = 0; k0 < 256; k0 += 32) {
    bf16x8 u0 = *(const bf16x8*)g0;
    bf16x8 u1 = *(const bf16x8*)g1;
    bf16x8 v0 = *(const bf16x8*)(g0 + 64 * 256);
    bf16x8 v1 = *(const bf16x8*)(g1 + 64 * 256);
    bf16x8 m0, m1;
#pragma unroll
    for (int e = 0; e < 8; e++) {
      m0[e] = (short)f2b(f0a * b2f((unsigned short)u0[e]) + f1a * b2f((unsigned short)u1[e]));
      m1[e] = (short)f2b(f0b * b2f((unsigned short)v0[e]) + f1b * b2f((unsigned short)v1[e]));
    }
    *(bf16x8*)((char*)As + t * 16) = m0;
    *(bf16x8*)((char*)As + 4096 + t * 16) = m1;
    glds16(gb, lB);
    glds16(gb + 64 * 256, lB + 4096);
    g0 += 32;
    g1 += 32;
    gb += 32;
    __syncthreads();
    bf16x8 a[4], b[4];
#pragma unroll
    for (int i = 0; i < 4; i++) a[i] = *(const bf16x8*)(pa + i * 512);
#pragma unroll
    for (int j = 0; j < 4; j++) b[j] = *(const bf16x8*)(pb + j * 512);
#pragma unroll
    for (int i = 0; i < 4; i++)
#pragma unroll
      for (int j = 0; j < 4; j++)
        acc[i][j] = __builtin_amdgcn_mfma_f32_16x16x32_bf16(a[i], b[j], acc[i][j], 0, 0, 0);
    __syncthreads();
  }

#pragma unroll
  for (int i = 0; i < 4; i++) {
#pragma unroll
    for (int j = 0; j < 4; j++) {
      const int col = col0 + wc * 64 + j * 16 + l15;
      const float bv_ = bias[col];
#pragma unroll
      for (int r = 0; r < 4; r++) {
        const long long row = row0 + wr * 64 + i * 16 + l4 * 4 + r;
        const long long idx = row * 256 + col;
        C[idx] = resid[idx] + acc[i][j][r] + bv_;
      }
    }
  }
}

// ---------------------------------------------------------------------------
// Transpose + bf16-cast the four 256x256 weights
// ---------------------------------------------------------------------------
__global__ void wtrans(const float* __restrict__ wq, const float* __restrict__ wk,
                       const float* __restrict__ wv, const float* __restrict__ wo,
                       unsigned short* __restrict__ wT)
{
  const float* w = blockIdx.z == 0 ? wq : blockIdx.z == 1 ? wk : blockIdx.z == 2 ? wv : wo;
  unsigned short* o = wT + (long long)blockIdx.z * 65536;
  __shared__ float tile[16][17];
  const int tx = threadIdx.x, ty = threadIdx.y;
  const int bx = blockIdx.x * 16, by = blockIdx.y * 16;
  tile[ty][tx] = w[(by + ty) * 256 + bx + tx];
  __syncthreads();
  o[(bx + ty) * 256 + (by + tx)] = f2b(tile[tx][ty]);
}

// ---------------------------------------------------------------------------
// Fused flash attention, swapped-operand, KV-SPLIT + counted vmcnt (T4).
// EXACT R11 configuration (measured 160us, MfmaUtil 38%, VGPR 128):
// grid 512: b = bid&7 (XCD pin), kh = (bid>>3)&1, qb = bid>>4.
// 2 blocks/CU (64KB LDS): K dbuf 2x16KB @0, V dbuf 2x16KB @32K.
// Raw barrier pair + s_waitcnt vmcnt(8) (never 0 in-loop).
// Shfl-free softmax common path: per-lane defer-max check (+8 threshold),
// per-lane l partials reduced once in the epilogue.
// Partials UNNORMALIZED + (m,l); gemm_out merges.
// ---------------------------------------------------------------------------
#define FL_LDS (64 * 1024)

__global__ __launch_bounds__(256, 2) void flash(
    const unsigned short* __restrict__ q,   // [B][4096][256] bf16 (scaled by log2e/16)
    const unsigned short* __restrict__ kk,  // [B][4096][256] bf16
    const unsigned short* __restrict__ vT,  // [B][256][4096] bf16, k-permuted per 32
    unsigned short* __restrict__ o0,        // [B][4096][256] partial, kh=0
    unsigned short* __restrict__ o1,        // [B][4096][256] partial, kh=1
    float2* __restrict__ ml0,               // [B*4096] (m,l) kh=0
    float2* __restrict__ ml1)               // [B*4096] (m,l) kh=1
{
  extern __shared__ char lds[];
  const int t = threadIdx.x;
  const int w = t >> 6;
  const int lane = t & 63;
  const int l15 = lane & 15, hi = lane >> 4;
  const int b = blockIdx.x & 7;
  const int kh = (blockIdx.x >> 3) & 1;
  const int qb = blockIdx.x >> 4;
  const long long qrow = (long long)b * 4096 + (long long)qb * 128 + w * 32;

  const unsigned short* kbase = kk + (long long)b * 4096 * 256 + (long long)kh * 2048 * 256;
  const unsigned short* vbase = vT + (long long)b * 256 * 4096 + kh * 2048;

  const int gs_k = (t & 31) ^ ((t >> 5) & 7);
  const unsigned short* Kst = kbase + (t >> 5) * 256 + gs_k * 8;
  const int gs_v = (t & 3) ^ ((t >> 2) & 3);
  const unsigned short* Vst = vbase + (long long)(t >> 2) * 4096 + gs_v * 8;

  bf16x8 Qf[2][8];
#pragma unroll
  for (int qg = 0; qg < 2; qg++) {
    const unsigned short* qp = q + (qrow + qg * 16 + l15) * 256 + hi * 8;
#pragma unroll
    for (int ks = 0; ks < 8; ks++) Qf[qg][ks] = *(const bf16x8*)(qp + ks * 32);
  }

  f32x4 O[2][16] = {};
  float mrow[2] = {-1e30f, -1e30f};
  float lrow[2] = {0.f, 0.f};  // per-lane partials (reduced in epilogue)

  auto stage = [&](int it, int c) {
    const unsigned short* ks_ = Kst + (long long)it * 32 * 256;
    const unsigned short* vs_ = Vst + it * 32;
    char* kd = lds + c * 16384 + w * 1024;
    char* vd = lds + 32768 + c * 16384 + w * 1024;
#pragma unroll
    for (int p = 0; p < 4; p++) {
      glds16(ks_ + p * 8 * 256, kd + p * 4096);
      glds16(vs_ + (long long)p * 64 * 4096, vd + p * 4096);
    }
  };

  stage(0, 0);

  for (int it = 0; it < 64; ++it) {
    const int cur = it & 1;
    __builtin_amdgcn_s_barrier();  // A: all waves done reading buf[cur^1]
    if (it < 63) {
      stage(it + 1, cur ^ 1);
      asm volatile("s_waitcnt vmcnt(8)" ::: "memory");  // tile-it loads done
    } else {
      asm volatile("s_waitcnt vmcnt(0)" ::: "memory");
    }
    __builtin_amdgcn_sched_barrier(0);
    __builtin_amdgcn_s_barrier();  // B: buf[cur] ready for all waves
    const char* Kb = lds + cur * 16384;
    const char* Vb = lds + 32768 + cur * 16384;

    f32x4 S[2][2] = {};
    __builtin_amdgcn_s_setprio(1);
#pragma unroll
    for (int ks = 0; ks < 8; ks++) {
#pragma unroll
      for (int j = 0; j < 2; j++) {
        bf16x8 Kf = *(const bf16x8*)(Kb + (j * 16 + l15) * 512 +
                                     ((ks * 64 + hi * 16) ^ ((l15 & 7) << 4)));
        S[0][j] = __builtin_amdgcn_mfma_f32_16x16x32_bf16(Kf, Qf[0][ks], S[0][j], 0, 0, 0);
        S[1][j] = __builtin_amdgcn_mfma_f32_16x16x32_bf16(Kf, Qf[1][ks], S[1][j], 0, 0, 0);
      }
    }
    __builtin_amdgcn_s_setprio(0);

    bf16x8 Pf8[2];
#pragma unroll
    for (int qg = 0; qg < 2; qg++) {
      const float mxl =
          fmaxf(fmaxf(fmaxf(S[qg][0][0], S[qg][0][1]), fmaxf(S[qg][0][2], S[qg][0][3])),
                fmaxf(fmaxf(S[qg][1][0], S[qg][1][1]), fmaxf(S[qg][1][2], S[qg][1][3])));
      if (!__all(mxl <= mrow[qg] + 8.f)) {
        float mx = fmaxf(mxl, __shfl_xor(mxl, 16, 64));
        mx = fmaxf(mx, __shfl_xor(mx, 32, 64));
        const float mn = fmaxf(mrow[qg], mx);
        const float rs_ = exp2f(mrow[qg] - mn);
        mrow[qg] = mn;
        lrow[qg] *= rs_;
#pragma unroll
        for (int dg = 0; dg < 16; dg++) O[qg][dg] *= rs_;
      }
      float sum = 0.f;
      float e[2][4];
#pragma unroll
      for (int j = 0; j < 2; j++)
#pragma unroll
        for (int r = 0; r < 4; r++) {
          e[j][r] = exp2f(S[qg][j][r] - mrow[qg]);
          sum += e[j][r];
        }
      lrow[qg] += sum;
      bf16x8 p;
#pragma unroll
      for (int j = 0; j < 2; j++)
#pragma unroll
        for (int r = 0; r < 4; r++) p[j * 4 + r] = (short)f2b(e[j][r]);
      Pf8[qg] = p;
    }

    __builtin_amdgcn_s_setprio(1);
#pragma unroll
    for (int dg = 0; dg < 16; dg++) {
      bf16x8 Vf8 = *(const bf16x8*)(Vb + (dg * 16 + l15) * 64 +
                                    ((hi * 16) ^ ((l15 & 3) << 4)));
      O[0][dg] = __builtin_amdgcn_mfma_f32_16x16x32_bf16(Vf8, Pf8[0], O[0][dg], 0, 0, 0);
      O[1][dg] = __builtin_amdgcn_mfma_f32_16x16x32_bf16(Vf8, Pf8[1], O[1][dg], 0, 0, 0);
    }
    __builtin_amdgcn_s_setprio(0);
  }

  unsigned short* const op = kh ? o1 : o0;
  float2* const mlp = kh ? ml1 : ml0;
  __syncthreads();
  char* const slab = lds + w * 16384;
#pragma unroll
  for (int qg = 0; qg < 2; qg++) {
    float lr = lrow[qg];
    lr += __shfl_xor(lr, 16, 64);
    lr += __shfl_xor(lr, 32, 64);
#pragma unroll
    for (int dg = 0; dg < 16; dg++) {
      f32x4 v = O[qg][dg];
      *(f32x4*)(slab + l15 * 1024 + ((dg * 64 + hi * 16) ^ ((l15 & 7) << 4))) = v;
    }
    if (hi == 0) mlp[qrow + qg * 16 + l15] = make_float2(mrow[qg], lr);
    const int qq = lane >> 2;
    const int dc = lane & 3;
    const long long orow = (qrow + qg * 16 + qq) * 256 + dc * 64;
#pragma unroll
    for (int half = 0; half < 8; half++) {
      bf16x8 pack;
#pragma unroll
      for (int di = 0; di < 2; di++) {
        f32x4 v = *(const f32x4*)(slab + qq * 1024 +
                                  ((dc * 256 + half * 32 + di * 16) ^ ((qq & 7) << 4)));
#pragma unroll
        for (int e2 = 0; e2 < 4; e2++) pack[di * 4 + e2] = (short)f2b(v[e2]);
      }
      *(bf16x8*)(op + orow + half * 8) = pack;
    }
    __syncthreads();
  }
}

// ---------------------------------------------------------------------------
extern "C" void kernel_launch(void* const* d_in, const int* in_sizes, int n_in,
                              void* d_out, int out_size, void* d_ws, size_t ws_size,
                              hipStream_t stream)
{
  const float* x = (const float*)d_in[0];
  const float* gamma = (const float*)d_in[1];
  const float* beta = (const float*)d_in[2];
  const float* wq = (const float*)d_in[3];
  const float* bq = (const float*)d_in[4];
  const float* wk = (const float*)d_in[5];
  const float* bk = (const float*)d_in[6];
  const float* wv = (const float*)d_in[7];
  const float* bv = (const float*)d_in[8];
  const float* wo = (const float*)d_in[9];
  const float* bo = (const float*)d_in[10];

  const int Cc = 256;
  const long long MR = 32768;  // 8 * 4096

  char* base = (char*)d_ws;
  size_t off = 0;
  auto take = [&](size_t bytes) -> char* {
    char* p = base + off;
    off = (off + bytes + 255) & ~(size_t)255;
    return p;
  };
  unsigned short* q   = (unsigned short*)take((size_t)MR * Cc * 2);  // scaled
  unsigned short* kk  = (unsigned short*)take((size_t)MR * Cc * 2);
  unsigned short* vT  = (unsigned short*)take((size_t)MR * Cc * 2);  // [B][C][4096] k-perm
  unsigned short* o0  = (unsigned short*)take((size_t)MR * Cc * 2);  // partial kh=0
  unsigned short* o1  = (unsigned short*)take((size_t)MR * Cc * 2);  // partial kh=1
  unsigned short* wT  = (unsigned short*)take(4ull * Cc * Cc * 2);
  float2* ml0 = (float2*)take((size_t)MR * sizeof(float2));
  float2* ml1 = (float2*)take((size_t)MR * sizeof(float2));

  wtrans<<<dim3(16, 16, 4), dim3(16, 16), 0, stream>>>(wq, wk, wv, wo, wT);

  const float qscale = 0.0625f * 1.44269504f;  // 1/sqrt(256) * log2(e)
  ln_qkv<<<dim3(2, 256), dim3(256), LQ_LDS, stream>>>(x, gamma, beta, wT, bq, bk, bv,
                                                      q, kk, vT, qscale);

  flash<<<dim3(512), dim3(256), FL_LDS, stream>>>(q, kk, vT, o0, o1, ml0, ml1);

  gemm_out<<<dim3(2, 256, 1), 256, 0, stream>>>(o0, o1, ml0, ml1, wT + 3 * 65536,
                                                (float*)d_out, bo, x);
}